// Round 8
// baseline (570.842 us; speedup 1.0000x reference)
//
#include <hip/hip_runtime.h>

#define DI __device__ __forceinline__

typedef __attribute__((ext_vector_type(8))) short bf16x8;  // 8 bf16 bit-patterns
typedef __attribute__((ext_vector_type(4))) short s16x4;
typedef __attribute__((ext_vector_type(4))) float f32x4;

DI short f2bs(float x){ unsigned u = __float_as_uint(x);
  return (short)((u + 0x7FFF + ((u >> 16) & 1)) >> 16); }          // RNE f32->bf16
DI float bs2f(short s){ return __uint_as_float(((unsigned)(unsigned short)s) << 16); }
DI f32x4 MFMA(bf16x8 a, bf16x8 b, f32x4 c){
  return __builtin_amdgcn_mfma_f32_16x16x32_bf16(a, b, c, 0, 0, 0);
}

// Problem constants
constexpr int NP   = 8192;
constexpr int NTOT = 16384;     // B*NP (reference flattens batch)
constexpr int M    = 4096;      // B*M_ROIS
constexpr int C    = 128;
constexpr int O    = 256;
constexpr int NS   = 32;
constexpr int GFS  = 136;       // gf LDS row stride (shorts): 272B
constexpr int VS   = 264;       // vst LDS row stride (shorts): 528B
constexpr float BNS = 0.99999500003749969f;  // 1/sqrt(1+1e-5)

// ---------------- K0a: features (B,C,NP) f32 -> fT bf16 [B*NP][C] ----------------
__global__ __launch_bounds__(256) void k_transpose(const float* __restrict__ feat,
                                                   short* __restrict__ fT){
  __shared__ float tile[128][65];
  int blk = blockIdx.x;
  int b  = blk >> 7;
  int n0 = (blk & 127) << 6;
  int t = threadIdx.x;
  int nn = t & 63, c4 = t >> 6;
  const float* src = feat + (size_t)b * C * NP;
  for(int i = 0; i < 32; i++){
    int c = c4 * 32 + i;
    tile[c][nn] = src[(size_t)c * NP + n0 + nn];
  }
  __syncthreads();
  int c2 = t & 127, nb = t >> 7;
  for(int j = 0; j < 32; j++){
    int n = nb + j * 2;
    fT[((size_t)(b * NP + n0 + n)) * C + c2] = f2bs(tile[c2][n]);
  }
}

// ---------------- K0b: pack weights ----------------
__global__ __launch_bounds__(256) void k_pack(
    const float* __restrict__ kw, const float* __restrict__ v1w,
    const float* __restrict__ v2w, const float* __restrict__ pw,
    const float* __restrict__ vcw, const float* __restrict__ qcw,
    const float* __restrict__ kcw, const float* __restrict__ qkcw,
    const float* __restrict__ cw1, const float* __restrict__ rw1,
    short* __restrict__ keyP, short* __restrict__ v1P,
    float* __restrict__ kgx, float* __restrict__ v1gx, float* __restrict__ pgx,
    short* __restrict__ v2b,
    short* __restrict__ gw,            // 4 x O x O bf16 (vc,qc,kc,qkc)
    short* __restrict__ fgw)           // 256 x 256 bf16 ([cw1;rw1])
{
  int i = blockIdx.x * 256 + threadIdx.x;
  if(i < O * C){
    int o = i >> 7, k = i & 127;
    keyP[i] = f2bs(kw[o*131 + 3 + k]);
    v1P[i]  = f2bs(v1w[o*131 + 3 + k]);
  }
  if(i < O){
    for(int j = 0; j < 3; j++){
      kgx [i*4+j] = kw [i*131 + j];
      v1gx[i*4+j] = v1w[i*131 + j];
      pgx [i*4+j] = pw [i*3 + j];
    }
    kgx[i*4+3] = 0.0f; v1gx[i*4+3] = 0.0f; pgx[i*4+3] = 0.0f;
  }
  if(i < O * O){
    v2b[i] = f2bs(v2w[i]);
    gw[0*O*O + i] = f2bs(vcw[i]);
    gw[1*O*O + i] = f2bs(qcw[i]);
    gw[2*O*O + i] = f2bs(kcw[i]);
    gw[3*O*O + i] = f2bs(qkcw[i]);
    fgw[i] = f2bs(i < 128*O ? cw1[i] : rw1[i - 128*O]);
  }
}

// ---------------- K1: ball query, 1 wave per query (exact f32) ----------------
__global__ __launch_bounds__(64) void k_ballq(const float* __restrict__ xyz,
                                              const float* __restrict__ nxyz,
                                              int* __restrict__ idxo,
                                              float* __restrict__ gxo){
#pragma clang fp contract(off)
  int m = blockIdx.x;
  int lane = threadIdx.x;
  float qx = nxyz[m*3+0], qy = nxyz[m*3+1], qz = nxyz[m*3+2];
  __shared__ int sel[NS];
  int cnt = 0;
  for(int base = 0; base < NTOT; base += 64){
    int p = base + lane;
    float dx = qx - xyz[p*3+0], dy = qy - xyz[p*3+1], dz = qz - xyz[p*3+2];
    float d2 = dx*dx + dy*dy;     // numpy order: (x^2+y^2)+z^2, no contraction
    d2 = d2 + dz*dz;
    bool pred = d2 < 2.56f;
    unsigned long long bal = __ballot(pred);
    if(pred){
      int pos = cnt + __popcll(bal & ((1ull << lane) - 1ull));
      if(pos < NS) sel[pos] = p;
    }
    cnt += __popcll(bal);
    if(cnt >= NS) break;          // wave-uniform
  }
  __syncthreads();
  if(lane < NS){
    int s = 0;
    if(cnt > 0) s = (lane < cnt) ? sel[lane] : sel[0];  // pad with first; empty -> 0
    idxo[m*NS + lane] = s;
    gxo[(m*NS+lane)*3+0] = xyz[s*3+0] - qx;
    gxo[(m*NS+lane)*3+1] = xyz[s*3+1] - qy;
    gxo[(m*NS+lane)*3+2] = xyz[s*3+2] - qz;
  }
}

// ---------------- K2: FULLY FUSED conv+gates+attn+fgate, 2 queries/block ----------------
__global__ __launch_bounds__(256, 2) void k_fused(
    const short* __restrict__ fT,
    const short* __restrict__ keyP, const short* __restrict__ v1P,
    const float* __restrict__ kgx, const float* __restrict__ v1gx,
    const float* __restrict__ pgx,
    const short* __restrict__ v2b, const short* __restrict__ gw,
    const short* __restrict__ fgw, const float* __restrict__ attw,
    const float* __restrict__ g1, const float* __restrict__ b1,
    const float* __restrict__ g2, const float* __restrict__ b2,
    const float* __restrict__ cb1, const float* __restrict__ cw2,
    const float* __restrict__ cb2,
    const float* __restrict__ rb1, const float* __restrict__ rw2,
    const float* __restrict__ rb2,
    const int* __restrict__ idxw, const float* __restrict__ gxw,
    float* __restrict__ outNF, float* __restrict__ outC, float* __restrict__ outR)
{
  int lq2 = blockIdx.x, t = threadIdx.x;
  int w = t >> 6, l = t & 63;
  int col = l & 15, kq = l >> 4;
  int ro = w * 64;
  __shared__ __align__(16) short gf[64 * GFS];    // 17408 B
  __shared__ __align__(16) short vst[64 * VS];    // 33792 B
  __shared__ float gxs[64 * 4];                   // 1024
  __shared__ int  sel[64];                        // 256
  __shared__ float attwL[4 * O];                  // 4096
  __shared__ float meanL[3][2][O];                // 6144
  __shared__ float gatesL[4][2][O];               // 8192
  __shared__ float scoreP[4][4][64];              // 4096
  __shared__ float attnL[4][2][NS];               // 1024
  __shared__ float nfL[2][O];                     // 2048
  __shared__ float pgsum[4][2];                   // 32    total ~76.3 KB -> 2 blocks/CU
  int qg0 = lq2 * 2;
  if(t < 64){
    int qi = t >> 5, n = t & 31;
    int gq = qg0 + qi;
    sel[t] = idxw[gq*NS + n];
    gxs[t*4+0] = gxw[(gq*NS+n)*3+0];
    gxs[t*4+1] = gxw[(gq*NS+n)*3+1];
    gxs[t*4+2] = gxw[(gq*NS+n)*3+2];
    gxs[t*4+3] = 0.0f;
  }
  for(int i = t; i < 4*O; i += 256) attwL[i] = attw[i];
  __syncthreads();
  // gather features: wave w -> rows w*16..w*16+15; lane covers 2 channels (4B)
  for(int i = 0; i < 16; i++){
    int n = w*16 + i;
    int p = sel[n];
    *(unsigned*)&gf[n*GFS + l*2] = *(const unsigned*)(fT + (size_t)p * C + l*2);
  }
  __syncthreads();

  const f32x4 vzero = {0.0f, 0.0f, 0.0f, 0.0f};

  // ======== v = relu(bn1(W_v1 @ [gx; feats])) -> vst ========
  {
    f32x4 acc[4][4];
    for(int mt=0;mt<4;mt++) for(int nt=0;nt<4;nt++) acc[mt][nt] = vzero;
    for(int ks = 0; ks < 4; ks++){
      bf16x8 bf[4];
      for(int nt=0;nt<4;nt++)
        bf[nt] = *(const bf16x8*)&gf[(nt*16+col)*GFS + ks*32 + kq*8];
      for(int mt = 0; mt < 4; mt++){
        bf16x8 a = *(const bf16x8*)(v1P + (size_t)(ro + mt*16 + col)*C + ks*32 + kq*8);
        for(int nt=0;nt<4;nt++) acc[mt][nt] = MFMA(a, bf[nt], acc[mt][nt]);
      }
    }
    for(int mt=0;mt<4;mt++){
      int o0 = ro + mt*16 + kq*4;
      f32x4 vg[4];
      float gg[4], bb[4];
      for(int r=0;r<4;r++){ vg[r] = *(const f32x4*)(v1gx + (o0+r)*4);
                            gg[r] = g1[o0+r]; bb[r] = b1[o0+r]; }
      for(int nt=0;nt<4;nt++){
        int n = nt*16 + col;
        float gx0 = gxs[n*4+0], gx1 = gxs[n*4+1], gx2 = gxs[n*4+2];
        s16x4 pk;
        for(int r=0;r<4;r++){
          float x = acc[mt][nt][r] + vg[r][0]*gx0 + vg[r][1]*gx1 + vg[r][2]*gx2;
          pk[r] = f2bs(fmaxf(gg[r]*(x * BNS) + bb[r], 0.0f));
        }
        *(s16x4*)&vst[n*VS + o0] = pk;
      }
    }
  }

  // ======== key = relu(W_key @ [gx; feats]) (kept f32 in regs) + means ========
  f32x4 accK[4][4];
  {
    for(int mt=0;mt<4;mt++) for(int nt=0;nt<4;nt++) accK[mt][nt] = vzero;
    for(int ks = 0; ks < 4; ks++){
      bf16x8 bf[4];
      for(int nt=0;nt<4;nt++)
        bf[nt] = *(const bf16x8*)&gf[(nt*16+col)*GFS + ks*32 + kq*8];
      for(int mt = 0; mt < 4; mt++){
        bf16x8 a = *(const bf16x8*)(keyP + (size_t)(ro + mt*16 + col)*C + ks*32 + kq*8);
        for(int nt=0;nt<4;nt++) accK[mt][nt] = MFMA(a, bf[nt], accK[mt][nt]);
      }
    }
    for(int mt=0;mt<4;mt++){
      int o0 = ro + mt*16 + kq*4;
      f32x4 kg[4], pg[4];
      for(int r=0;r<4;r++){ kg[r] = *(const f32x4*)(kgx + (o0+r)*4);
                            pg[r] = *(const f32x4*)(pgx + (o0+r)*4); }
      for(int qi=0; qi<2; qi++){
        float sp[4]={0,0,0,0}, sk[4]={0,0,0,0}, spk[4]={0,0,0,0};
        for(int h=0; h<2; h++){
          int nt = qi*2 + h;
          int n  = nt*16 + col;
          float gx0 = gxs[n*4+0], gx1 = gxs[n*4+1], gx2 = gxs[n*4+2];
          for(int r=0;r<4;r++){
            float kk = fmaxf(accK[mt][nt][r] + kg[r][0]*gx0 + kg[r][1]*gx1 + kg[r][2]*gx2, 0.0f);
            accK[mt][nt][r] = kk;
            float pv = fmaxf(pg[r][0]*gx0 + pg[r][1]*gx1 + pg[r][2]*gx2, 0.0f);
            sp[r] += pv; sk[r] += kk; spk[r] += pv*kk;
          }
        }
        for(int r=0;r<4;r++){
          float a = sp[r], b = sk[r], c = spk[r];
          for(int msk=1; msk<16; msk<<=1){
            a += __shfl_xor(a, msk); b += __shfl_xor(b, msk); c += __shfl_xor(c, msk);
          }
          if(col == 0){
            meanL[0][qi][o0+r] = a * 0.03125f;
            meanL[1][qi][o0+r] = b * 0.03125f;
            meanL[2][qi][o0+r] = c * 0.03125f;
          }
        }
      }
    }
  }
  __syncthreads();   // b1: vst + meanL visible

  // ======== gates: wave w computes gate w = sigmoid(W_w @ mean_type(w)) ========
  {
    int mty = (w < 2) ? 0 : ((w == 2) ? 1 : 2);
    f32x4 ag[16];
    for(int i=0;i<16;i++) ag[i] = vzero;
    for(int ks = 0; ks < 8; ks++){
      union { bf16x8 v; short e[8]; } u;
      for(int j = 0; j < 8; j++){
        int k = ks*32 + kq*8 + j;
        u.e[j] = (col < 2) ? f2bs(meanL[mty][col][k]) : (short)0;
      }
      for(int mt16 = 0; mt16 < 16; mt16++){
        bf16x8 a = *(const bf16x8*)(gw + (size_t)w*O*O + (size_t)(mt16*16 + col)*O + ks*32 + kq*8);
        ag[mt16] = MFMA(a, u.v, ag[mt16]);
      }
    }
    if(col < 2){
      for(int mt16=0;mt16<16;mt16++) for(int r=0;r<4;r++){
        int oo = mt16*16 + kq*4 + r;
        gatesL[w][col][oo] = 1.0f / (1.0f + expf(-ag[mt16][r]));
      }
    }
  }
  __syncthreads();   // b2: gatesL visible

  // ======== scores: s[h][n] partials from this wave's 64 rows ========
  {
    float sc[4][4];
    for(int h=0;h<4;h++) for(int nt=0;nt<4;nt++) sc[h][nt] = 0.0f;
    for(int mt=0;mt<4;mt++){
      int o0 = ro + mt*16 + kq*4;
      f32x4 pg[4];
      float aw[4][4], qcv[2][4], kcv[2][4], qkv[2][4];
      for(int r=0;r<4;r++){
        pg[r] = *(const f32x4*)(pgx + (o0+r)*4);
        for(int h=0;h<4;h++) aw[h][r] = attwL[h*O + o0 + r];
        for(int qi=0;qi<2;qi++){
          qcv[qi][r] = gatesL[1][qi][o0+r];
          kcv[qi][r] = gatesL[2][qi][o0+r];
          qkv[qi][r] = gatesL[3][qi][o0+r];
        }
      }
      for(int nt=0;nt<4;nt++){
        int qi = nt >> 1;
        int n  = nt*16 + col;
        float gx0 = gxs[n*4+0], gx1 = gxs[n*4+1], gx2 = gxs[n*4+2];
        for(int r=0;r<4;r++){
          float pos = fmaxf(pg[r][0]*gx0 + pg[r][1]*gx1 + pg[r][2]*gx2, 0.0f);
          float key = accK[mt][nt][r];
          float em  = pos*qcv[qi][r] + key*kcv[qi][r] + pos*key*qkv[qi][r];
          for(int h=0;h<4;h++) sc[h][nt] += aw[h][r]*em;
        }
      }
    }
    for(int h=0;h<4;h++) for(int nt=0;nt<4;nt++){
      float v = sc[h][nt];
      v += __shfl_xor(v, 16); v += __shfl_xor(v, 32);
      if(kq == 0) scoreP[w][h][nt*16 + col] = v;
    }
  }
  __syncthreads();   // b3: scoreP visible

  // ======== softmax: wave w = head w; lanes: qi = l>>5, nn = l&31 ========
  {
    float s = scoreP[0][w][l] + scoreP[1][w][l] + scoreP[2][w][l] + scoreP[3][w][l];
    float mx = s;
    for(int msk=1; msk<32; msk<<=1) mx = fmaxf(mx, __shfl_xor(mx, msk));
    float e = expf(s - mx);
    float su = e;
    for(int msk=1; msk<32; msk<<=1) su += __shfl_xor(su, msk);
    attnL[w][l>>5][l&31] = e / su;
  }
  __syncthreads();   // b4: attnL visible

  // ======== val = relu(bn2(W_v2 @ v)); nf = sum_n (val + pos*vc)*attn ========
  {
    f32x4 acc[4][4];
    for(int mt=0;mt<4;mt++) for(int nt=0;nt<4;nt++) acc[mt][nt] = vzero;
    for(int ks = 0; ks < 8; ks++){
      bf16x8 bf[4];
      for(int nt=0;nt<4;nt++)
        bf[nt] = *(const bf16x8*)&vst[(nt*16+col)*VS + ks*32 + kq*8];
      for(int mt = 0; mt < 4; mt++){
        bf16x8 a = *(const bf16x8*)(v2b + (size_t)(ro + mt*16 + col)*O + ks*32 + kq*8);
        for(int nt=0;nt<4;nt++) acc[mt][nt] = MFMA(a, bf[nt], acc[mt][nt]);
      }
    }
    for(int mt=0;mt<4;mt++){
      int o0 = ro + mt*16 + kq*4;
      f32x4 pg[4];
      float gg[4], bb[4], vcv[2][4];
      for(int r=0;r<4;r++){
        pg[r] = *(const f32x4*)(pgx + (o0+r)*4);
        gg[r] = g2[o0+r]; bb[r] = b2[o0+r];
        vcv[0][r] = gatesL[0][0][o0+r];
        vcv[1][r] = gatesL[0][1][o0+r];
      }
      float nf2[2][4];
      for(int qi=0;qi<2;qi++) for(int r=0;r<4;r++) nf2[qi][r] = 0.0f;
      for(int nt=0;nt<4;nt++){
        int qi = nt >> 1;
        int nn = (nt&1)*16 + col;
        int n  = nt*16 + col;
        float gx0 = gxs[n*4+0], gx1 = gxs[n*4+1], gx2 = gxs[n*4+2];
        float at = attnL[w][qi][nn];
        for(int r=0;r<4;r++){
          float val = fmaxf(gg[r]*(acc[mt][nt][r] * BNS) + bb[r], 0.0f);
          float pos = fmaxf(pg[r][0]*gx0 + pg[r][1]*gx1 + pg[r][2]*gx2, 0.0f);
          nf2[qi][r] += (val + pos*vcv[qi][r]) * at;
        }
      }
      for(int qi=0;qi<2;qi++) for(int r=0;r<4;r++){
        float v = nf2[qi][r];
        v += __shfl_xor(v, 1); v += __shfl_xor(v, 2);
        v += __shfl_xor(v, 4); v += __shfl_xor(v, 8);
        if(col == 0) nfL[qi][o0+r] = v;
      }
    }
  }
  __syncthreads();   // b5: nfL visible

  // ======== fgate: stacked [cw1;rw1] MFMA; wave w -> rows w*64..w*64+63 ========
  {
    f32x4 ac[4];
    for(int i=0;i<4;i++) ac[i] = vzero;
    for(int ks = 0; ks < 8; ks++){
      union { bf16x8 v; short e[8]; } u;
      for(int j = 0; j < 8; j++){
        int k = ks*32 + kq*8 + j;
        u.e[j] = (col < 2) ? f2bs(nfL[col][k]) : (short)0;
      }
      for(int mt = 0; mt < 4; mt++){
        bf16x8 a = *(const bf16x8*)(fgw + (size_t)(w*64 + mt*16 + col)*O + ks*32 + kq*8);
        ac[mt] = MFMA(a, u.v, ac[mt]);
      }
    }
    bool cls = (w < 2);
    const float* b1p = cls ? cb1 : rb1;
    const float* w2p = cls ? cw2 : rw2;
    int jbase = (cls ? w : (w - 2)) * 64;
    float pp = 0.0f;
    for(int mt=0;mt<4;mt++) for(int r=0;r<4;r++){
      int j = jbase + mt*16 + kq*4 + r;
      pp += fmaxf(ac[mt][r] + b1p[j], 0.0f) * w2p[j];
    }
    pp += __shfl_xor(pp, 16); pp += __shfl_xor(pp, 32);
    if(kq == 0 && col < 2) pgsum[w][col] = pp;
  }
  __syncthreads();   // b6: pgsum visible

  // ======== final outputs ========
  {
    for(int qi = 0; qi < 2; qi++){
      float sC = 1.0f / (1.0f + expf(-(pgsum[0][qi] + pgsum[1][qi] + cb2[0])));
      float sR = 1.0f / (1.0f + expf(-(pgsum[2][qi] + pgsum[3][qi] + rb2[0])));
      int q = qg0 + qi;
      float nv = nfL[qi][t];
      outNF[(size_t)q*O + t] = nv;
      outC [(size_t)q*O + t] = nv * sC;
      outR [(size_t)q*O + t] = nv * sR;
    }
  }
}

extern "C" void kernel_launch(void* const* d_in, const int* in_sizes, int n_in,
                              void* d_out, int out_size, void* d_ws, size_t ws_size,
                              hipStream_t stream)
{
  const float* xyz  = (const float*)d_in[0];
  const float* nxyz = (const float*)d_in[1];
  const float* feat = (const float*)d_in[2];
  const float* posw = (const float*)d_in[3];
  const float* keyw = (const float*)d_in[4];
  const float* v1w  = (const float*)d_in[5];
  const float* bn1g = (const float*)d_in[6];
  const float* bn1b = (const float*)d_in[7];
  const float* v2w  = (const float*)d_in[8];
  const float* bn2g = (const float*)d_in[9];
  const float* bn2b = (const float*)d_in[10];
  const float* attw = (const float*)d_in[11];
  const float* kcw  = (const float*)d_in[12];
  const float* qcw  = (const float*)d_in[13];
  const float* qkcw = (const float*)d_in[14];
  const float* vcw  = (const float*)d_in[15];
  const float* cw1  = (const float*)d_in[16];
  const float* cb1  = (const float*)d_in[17];
  const float* cw2  = (const float*)d_in[18];
  const float* cb2  = (const float*)d_in[19];
  const float* rw1  = (const float*)d_in[20];
  const float* rb1  = (const float*)d_in[21];
  const float* rw2  = (const float*)d_in[22];
  const float* rb2  = (const float*)d_in[23];

  char* p = (char*)d_ws;
  auto alloc = [&](size_t bytes){ char* r = p; p += (bytes + 255) & ~size_t(255); return r; };
  short* fT    = (short*)alloc((size_t)NTOT*C*2);
  short* keyP  = (short*)alloc((size_t)O*C*2);
  short* v1P   = (short*)alloc((size_t)O*C*2);
  float* kgx   = (float*)alloc((size_t)O*4*4);
  float* v1gx  = (float*)alloc((size_t)O*4*4);
  float* pgx   = (float*)alloc((size_t)O*4*4);
  short* v2b   = (short*)alloc((size_t)O*O*2);
  short* gw    = (short*)alloc((size_t)4*O*O*2);
  short* fgw   = (short*)alloc((size_t)O*O*2);
  int*   idxw  = (int*)  alloc((size_t)M*NS*4);
  float* gxw   = (float*)alloc((size_t)M*NS*3*4);

  float* outNF = (float*)d_out;
  float* outC  = outNF + (size_t)M*O;
  float* outR  = outC  + (size_t)M*O;

  k_transpose<<<256, 256, 0, stream>>>(feat, fT);
  k_pack     <<<256, 256, 0, stream>>>(keyw, v1w, v2w, posw, vcw, qcw, kcw, qkcw, cw1, rw1,
                                       keyP, v1P, kgx, v1gx, pgx, v2b, gw, fgw);
  k_ballq    <<<M,   64,  0, stream>>>(xyz, nxyz, idxw, gxw);
  k_fused    <<<M/2, 256, 0, stream>>>(fT, keyP, v1P, kgx, v1gx, pgx, v2b, gw, fgw, attw,
                                       bn1g, bn1b, bn2g, bn2b,
                                       cb1, cw2, cb2, rb1, rw2, rb2,
                                       idxw, gxw, outNF, outC, outR);
}

// Round 10
// 524.656 us; speedup vs baseline: 1.0880x; 1.0880x over previous
//
#include <hip/hip_runtime.h>

#define DI __device__ __forceinline__

typedef __attribute__((ext_vector_type(8))) short bf16x8;  // 8 bf16 bit-patterns
typedef __attribute__((ext_vector_type(4))) short s16x4;
typedef __attribute__((ext_vector_type(4))) float f32x4;

DI short f2bs(float x){ unsigned u = __float_as_uint(x);
  return (short)((u + 0x7FFF + ((u >> 16) & 1)) >> 16); }          // RNE f32->bf16
DI float bs2f(short s){ return __uint_as_float(((unsigned)(unsigned short)s) << 16); }
DI f32x4 MFMA(bf16x8 a, bf16x8 b, f32x4 c){
  return __builtin_amdgcn_mfma_f32_16x16x32_bf16(a, b, c, 0, 0, 0);
}

// Problem constants
constexpr int NP   = 8192;
constexpr int NTOT = 16384;     // B*NP (reference flattens batch)
constexpr int M    = 4096;      // B*M_ROIS
constexpr int C    = 128;
constexpr int O    = 256;
constexpr int NS   = 32;
constexpr int GFS  = 136;       // gf LDS row stride (shorts): 272B
constexpr int VS   = 264;       // vst LDS row stride (shorts): 528B
constexpr float BNS = 0.99999500003749969f;  // 1/sqrt(1+1e-5)

// ---------------- K0a: features (B,C,NP) f32 -> fT bf16 [B*NP][C] ----------------
__global__ __launch_bounds__(256) void k_transpose(const float* __restrict__ feat,
                                                   short* __restrict__ fT){
  __shared__ float tile[128][65];
  int blk = blockIdx.x;
  int b  = blk >> 7;
  int n0 = (blk & 127) << 6;
  int t = threadIdx.x;
  int nn = t & 63, c4 = t >> 6;
  const float* src = feat + (size_t)b * C * NP;
  for(int i = 0; i < 32; i++){
    int c = c4 * 32 + i;
    tile[c][nn] = src[(size_t)c * NP + n0 + nn];
  }
  __syncthreads();
  int c2 = t & 127, nb = t >> 7;
  for(int j = 0; j < 32; j++){
    int n = nb + j * 2;
    fT[((size_t)(b * NP + n0 + n)) * C + c2] = f2bs(tile[c2][n]);
  }
}

// ---------------- K0b: pack weights ----------------
__global__ __launch_bounds__(256) void k_pack(
    const float* __restrict__ kw, const float* __restrict__ v1w,
    const float* __restrict__ v2w, const float* __restrict__ pw,
    const float* __restrict__ vcw, const float* __restrict__ qcw,
    const float* __restrict__ kcw, const float* __restrict__ qkcw,
    const float* __restrict__ cw1, const float* __restrict__ rw1,
    short* __restrict__ keyP, short* __restrict__ v1P,
    float* __restrict__ kgx, float* __restrict__ v1gx, float* __restrict__ pgx,
    short* __restrict__ v2b,
    short* __restrict__ gw,            // 4 x O x O bf16 (vc,qc,kc,qkc)
    short* __restrict__ fgw)           // 256 x 256 bf16 ([cw1;rw1])
{
  int i = blockIdx.x * 256 + threadIdx.x;
  if(i < O * C){
    int o = i >> 7, k = i & 127;
    keyP[i] = f2bs(kw[o*131 + 3 + k]);
    v1P[i]  = f2bs(v1w[o*131 + 3 + k]);
  }
  if(i < O){
    for(int j = 0; j < 3; j++){
      kgx [i*4+j] = kw [i*131 + j];
      v1gx[i*4+j] = v1w[i*131 + j];
      pgx [i*4+j] = pw [i*3 + j];
    }
    kgx[i*4+3] = 0.0f; v1gx[i*4+3] = 0.0f; pgx[i*4+3] = 0.0f;
  }
  if(i < O * O){
    v2b[i] = f2bs(v2w[i]);
    gw[0*O*O + i] = f2bs(vcw[i]);
    gw[1*O*O + i] = f2bs(qcw[i]);
    gw[2*O*O + i] = f2bs(kcw[i]);
    gw[3*O*O + i] = f2bs(qkcw[i]);
    fgw[i] = f2bs(i < 128*O ? cw1[i] : rw1[i - 128*O]);
  }
}

// ---------------- K1: ball query, 1 wave per query (exact f32) ----------------
__global__ __launch_bounds__(64) void k_ballq(const float* __restrict__ xyz,
                                              const float* __restrict__ nxyz,
                                              int* __restrict__ idxo,
                                              float* __restrict__ gxo){
#pragma clang fp contract(off)
  int m = blockIdx.x;
  int lane = threadIdx.x;
  float qx = nxyz[m*3+0], qy = nxyz[m*3+1], qz = nxyz[m*3+2];
  __shared__ int sel[NS];
  int cnt = 0;
  for(int base = 0; base < NTOT; base += 64){
    int p = base + lane;
    float dx = qx - xyz[p*3+0], dy = qy - xyz[p*3+1], dz = qz - xyz[p*3+2];
    float d2 = dx*dx + dy*dy;     // numpy order: (x^2+y^2)+z^2, no contraction
    d2 = d2 + dz*dz;
    bool pred = d2 < 2.56f;
    unsigned long long bal = __ballot(pred);
    if(pred){
      int pos = cnt + __popcll(bal & ((1ull << lane) - 1ull));
      if(pos < NS) sel[pos] = p;
    }
    cnt += __popcll(bal);
    if(cnt >= NS) break;          // wave-uniform
  }
  __syncthreads();
  if(lane < NS){
    int s = 0;
    if(cnt > 0) s = (lane < cnt) ? sel[lane] : sel[0];  // pad with first; empty -> 0
    idxo[m*NS + lane] = s;
    gxo[(m*NS+lane)*3+0] = xyz[s*3+0] - qx;
    gxo[(m*NS+lane)*3+1] = xyz[s*3+1] - qy;
    gxo[(m*NS+lane)*3+2] = xyz[s*3+2] - qz;
  }
}

// ---------------- K2: FULLY FUSED — key stashed bf16 in vst; v reuses vst after scores ----
__global__ __launch_bounds__(256, 2) void k_fused(
    const short* __restrict__ fT,
    const short* __restrict__ keyP, const short* __restrict__ v1P,
    const float* __restrict__ kgx, const float* __restrict__ v1gx,
    const float* __restrict__ pgx,
    const short* __restrict__ v2b, const short* __restrict__ gw,
    const short* __restrict__ fgw, const float* __restrict__ attw,
    const float* __restrict__ g1, const float* __restrict__ b1,
    const float* __restrict__ g2, const float* __restrict__ b2,
    const float* __restrict__ cb1, const float* __restrict__ cw2,
    const float* __restrict__ cb2,
    const float* __restrict__ rb1, const float* __restrict__ rw2,
    const float* __restrict__ rb2,
    const int* __restrict__ idxw, const float* __restrict__ gxw,
    float* __restrict__ outNF, float* __restrict__ outC, float* __restrict__ outR)
{
  int lq2 = blockIdx.x, t = threadIdx.x;
  int w = t >> 6, l = t & 63;
  int col = l & 15, kq = l >> 4;
  int ro = w * 64;
  __shared__ __align__(16) short gf[64 * GFS];    // 17408 B
  __shared__ __align__(16) short vst[64 * VS];    // 33792 B (key -> then v)
  __shared__ float gxs[64 * 4];                   // 1024
  __shared__ int  sel[64];                        // 256
  __shared__ float attwL[4 * O];                  // 4096
  __shared__ float meanL[3][2][O];                // 6144
  __shared__ float gatesL[4][2][O];               // 8192
  __shared__ float scoreP[4][4][64];              // 4096
  __shared__ float attnL[4][2][NS];               // 1024
  __shared__ float nfL[2][O];                     // 2048
  __shared__ float pgsum[4][2];                   // 32    total ~78 KB -> 2 blocks/CU
  int qg0 = lq2 * 2;
  if(t < 64){
    int qi = t >> 5, n = t & 31;
    int gq = qg0 + qi;
    sel[t] = idxw[gq*NS + n];
    gxs[t*4+0] = gxw[(gq*NS+n)*3+0];
    gxs[t*4+1] = gxw[(gq*NS+n)*3+1];
    gxs[t*4+2] = gxw[(gq*NS+n)*3+2];
    gxs[t*4+3] = 0.0f;
  }
  for(int i = t; i < 4*O; i += 256) attwL[i] = attw[i];
  __syncthreads();
  // gather features: wave w -> rows w*16..w*16+15; lane covers 2 channels (4B)
  for(int i = 0; i < 16; i++){
    int n = w*16 + i;
    int p = sel[n];
    *(unsigned*)&gf[n*GFS + l*2] = *(const unsigned*)(fT + (size_t)p * C + l*2);
  }
  __syncthreads();

  const f32x4 vzero = {0.0f, 0.0f, 0.0f, 0.0f};

  // ======== stage K: key conv -> bf16 key in vst; means(pos,key,poskey) -> meanL ========
  {
    f32x4 acc[4][4];
    for(int mt=0;mt<4;mt++) for(int nt=0;nt<4;nt++) acc[mt][nt] = vzero;
    for(int ks = 0; ks < 4; ks++){
      bf16x8 bf[4];
      for(int nt=0;nt<4;nt++)
        bf[nt] = *(const bf16x8*)&gf[(nt*16+col)*GFS + ks*32 + kq*8];
      for(int mt = 0; mt < 4; mt++){
        bf16x8 a = *(const bf16x8*)(keyP + (size_t)(ro + mt*16 + col)*C + ks*32 + kq*8);
        for(int nt=0;nt<4;nt++) acc[mt][nt] = MFMA(a, bf[nt], acc[mt][nt]);
      }
    }
    for(int mt=0;mt<4;mt++){
      int o0 = ro + mt*16 + kq*4;
      f32x4 kg[4], pg[4];
      for(int r=0;r<4;r++){ kg[r] = *(const f32x4*)(kgx + (o0+r)*4);
                            pg[r] = *(const f32x4*)(pgx + (o0+r)*4); }
      for(int qi=0; qi<2; qi++){
        float sp[4]={0,0,0,0}, sk[4]={0,0,0,0}, spk[4]={0,0,0,0};
        for(int h=0; h<2; h++){
          int nt = qi*2 + h;
          int n  = nt*16 + col;
          float gx0 = gxs[n*4+0], gx1 = gxs[n*4+1], gx2 = gxs[n*4+2];
          s16x4 pk;
          for(int r=0;r<4;r++){
            float kk = fmaxf(acc[mt][nt][r] + kg[r][0]*gx0 + kg[r][1]*gx1 + kg[r][2]*gx2, 0.0f);
            float pv = fmaxf(pg[r][0]*gx0 + pg[r][1]*gx1 + pg[r][2]*gx2, 0.0f);
            pk[r] = f2bs(kk);
            sp[r] += pv; sk[r] += kk; spk[r] += pv*kk;
          }
          *(s16x4*)&vst[n*VS + o0] = pk;
        }
        for(int r=0;r<4;r++){
          float a = sp[r], b = sk[r], c = spk[r];
          for(int msk=1; msk<16; msk<<=1){
            a += __shfl_xor(a, msk); b += __shfl_xor(b, msk); c += __shfl_xor(c, msk);
          }
          if(col == 0){
            meanL[0][qi][o0+r] = a * 0.03125f;
            meanL[1][qi][o0+r] = b * 0.03125f;
            meanL[2][qi][o0+r] = c * 0.03125f;
          }
        }
      }
    }
  }
  __syncthreads();   // b1: vst(key) + meanL visible

  // ======== stage D: gates: wave w -> gate w = sigmoid(W_w @ mean_type(w)) ========
  {
    int mty = (w < 2) ? 0 : ((w == 2) ? 1 : 2);
    f32x4 ag[16];
    for(int i=0;i<16;i++) ag[i] = vzero;
    for(int ks = 0; ks < 8; ks++){
      union { bf16x8 v; short e[8]; } u;
      for(int j = 0; j < 8; j++){
        int k = ks*32 + kq*8 + j;
        u.e[j] = (col < 2) ? f2bs(meanL[mty][col][k]) : (short)0;
      }
      for(int mt16 = 0; mt16 < 16; mt16++){
        bf16x8 a = *(const bf16x8*)(gw + (size_t)w*O*O + (size_t)(mt16*16 + col)*O + ks*32 + kq*8);
        ag[mt16] = MFMA(a, u.v, ag[mt16]);
      }
    }
    if(col < 2){
      for(int mt16=0;mt16<16;mt16++) for(int r=0;r<4;r++){
        int oo = mt16*16 + kq*4 + r;
        gatesL[w][col][oo] = 1.0f / (1.0f + expf(-ag[mt16][r]));
      }
    }
  }
  __syncthreads();   // b2: gatesL visible

  // ======== stage E: scores — key read back (bf16) from vst ========
  {
    float sc[4][4];
    for(int h=0;h<4;h++) for(int nt=0;nt<4;nt++) sc[h][nt] = 0.0f;
    for(int mt=0;mt<4;mt++){
      int o0 = ro + mt*16 + kq*4;
      f32x4 pg[4];
      float aw[4][4], qcv[2][4], kcv[2][4], qkv[2][4];
      for(int r=0;r<4;r++){
        pg[r] = *(const f32x4*)(pgx + (o0+r)*4);
        for(int h=0;h<4;h++) aw[h][r] = attwL[h*O + o0 + r];
        for(int qi=0;qi<2;qi++){
          qcv[qi][r] = gatesL[1][qi][o0+r];
          kcv[qi][r] = gatesL[2][qi][o0+r];
          qkv[qi][r] = gatesL[3][qi][o0+r];
        }
      }
      for(int nt=0;nt<4;nt++){
        int qi = nt >> 1;
        int n  = nt*16 + col;
        float gx0 = gxs[n*4+0], gx1 = gxs[n*4+1], gx2 = gxs[n*4+2];
        s16x4 kv = *(const s16x4*)&vst[n*VS + o0];
        for(int r=0;r<4;r++){
          float key = bs2f(kv[r]);
          float pos = fmaxf(pg[r][0]*gx0 + pg[r][1]*gx1 + pg[r][2]*gx2, 0.0f);
          float em  = pos*qcv[qi][r] + key*kcv[qi][r] + pos*key*qkv[qi][r];
          for(int h=0;h<4;h++) sc[h][nt] += aw[h][r]*em;
        }
      }
    }
    for(int h=0;h<4;h++) for(int nt=0;nt<4;nt++){
      float v = sc[h][nt];
      v += __shfl_xor(v, 16); v += __shfl_xor(v, 32);
      if(kq == 0) scoreP[w][h][nt*16 + col] = v;
    }
  }
  __syncthreads();   // b3: scoreP visible; all vst(key) reads done

  // ======== stage F: softmax: wave w = head w ========
  {
    float s = scoreP[0][w][l] + scoreP[1][w][l] + scoreP[2][w][l] + scoreP[3][w][l];
    float mx = s;
    for(int msk=1; msk<32; msk<<=1) mx = fmaxf(mx, __shfl_xor(mx, msk));
    float e = expf(s - mx);
    float su = e;
    for(int msk=1; msk<32; msk<<=1) su += __shfl_xor(su, msk);
    attnL[w][l>>5][l&31] = e / su;
  }
  __syncthreads();   // b4: attnL visible; safe to overwrite vst

  // ======== stage B: v = relu(bn1(W_v1 @ [gx; feats])) -> vst (reuse) ========
  {
    f32x4 acc[4][4];
    for(int mt=0;mt<4;mt++) for(int nt=0;nt<4;nt++) acc[mt][nt] = vzero;
    for(int ks = 0; ks < 4; ks++){
      bf16x8 bf[4];
      for(int nt=0;nt<4;nt++)
        bf[nt] = *(const bf16x8*)&gf[(nt*16+col)*GFS + ks*32 + kq*8];
      for(int mt = 0; mt < 4; mt++){
        bf16x8 a = *(const bf16x8*)(v1P + (size_t)(ro + mt*16 + col)*C + ks*32 + kq*8);
        for(int nt=0;nt<4;nt++) acc[mt][nt] = MFMA(a, bf[nt], acc[mt][nt]);
      }
    }
    for(int mt=0;mt<4;mt++){
      int o0 = ro + mt*16 + kq*4;
      f32x4 vg[4];
      float gg[4], bb[4];
      for(int r=0;r<4;r++){ vg[r] = *(const f32x4*)(v1gx + (o0+r)*4);
                            gg[r] = g1[o0+r]; bb[r] = b1[o0+r]; }
      for(int nt=0;nt<4;nt++){
        int n = nt*16 + col;
        float gx0 = gxs[n*4+0], gx1 = gxs[n*4+1], gx2 = gxs[n*4+2];
        s16x4 pk;
        for(int r=0;r<4;r++){
          float x = acc[mt][nt][r] + vg[r][0]*gx0 + vg[r][1]*gx1 + vg[r][2]*gx2;
          pk[r] = f2bs(fmaxf(gg[r]*(x * BNS) + bb[r], 0.0f));
        }
        *(s16x4*)&vst[n*VS + o0] = pk;
      }
    }
  }
  __syncthreads();   // b5: vst(v) visible

  // ======== stage G: val = relu(bn2(W_v2 @ v)); nf accumulate ========
  {
    f32x4 acc[4][4];
    for(int mt=0;mt<4;mt++) for(int nt=0;nt<4;nt++) acc[mt][nt] = vzero;
    for(int ks = 0; ks < 8; ks++){
      bf16x8 bf[4];
      for(int nt=0;nt<4;nt++)
        bf[nt] = *(const bf16x8*)&vst[(nt*16+col)*VS + ks*32 + kq*8];
      for(int mt = 0; mt < 4; mt++){
        bf16x8 a = *(const bf16x8*)(v2b + (size_t)(ro + mt*16 + col)*O + ks*32 + kq*8);
        for(int nt=0;nt<4;nt++) acc[mt][nt] = MFMA(a, bf[nt], acc[mt][nt]);
      }
    }
    for(int mt=0;mt<4;mt++){
      int o0 = ro + mt*16 + kq*4;
      f32x4 pg[4];
      float gg[4], bb[4], vcv[2][4];
      for(int r=0;r<4;r++){
        pg[r] = *(const f32x4*)(pgx + (o0+r)*4);
        gg[r] = g2[o0+r]; bb[r] = b2[o0+r];
        vcv[0][r] = gatesL[0][0][o0+r];
        vcv[1][r] = gatesL[0][1][o0+r];
      }
      float nf2[2][4];
      for(int qi=0;qi<2;qi++) for(int r=0;r<4;r++) nf2[qi][r] = 0.0f;
      for(int nt=0;nt<4;nt++){
        int qi = nt >> 1;
        int nn = (nt&1)*16 + col;
        int n  = nt*16 + col;
        float gx0 = gxs[n*4+0], gx1 = gxs[n*4+1], gx2 = gxs[n*4+2];
        float at = attnL[w][qi][nn];
        for(int r=0;r<4;r++){
          float val = fmaxf(gg[r]*(acc[mt][nt][r] * BNS) + bb[r], 0.0f);
          float pos = fmaxf(pg[r][0]*gx0 + pg[r][1]*gx1 + pg[r][2]*gx2, 0.0f);
          nf2[qi][r] += (val + pos*vcv[qi][r]) * at;
        }
      }
      for(int qi=0;qi<2;qi++) for(int r=0;r<4;r++){
        float v = nf2[qi][r];
        v += __shfl_xor(v, 1); v += __shfl_xor(v, 2);
        v += __shfl_xor(v, 4); v += __shfl_xor(v, 8);
        if(col == 0) nfL[qi][o0+r] = v;
      }
    }
  }
  __syncthreads();   // b6: nfL visible

  // ======== stage H: fgate: stacked [cw1;rw1] MFMA ========
  {
    f32x4 ac[4];
    for(int i=0;i<4;i++) ac[i] = vzero;
    for(int ks = 0; ks < 8; ks++){
      union { bf16x8 v; short e[8]; } u;
      for(int j = 0; j < 8; j++){
        int k = ks*32 + kq*8 + j;
        u.e[j] = (col < 2) ? f2bs(nfL[col][k]) : (short)0;
      }
      for(int mt = 0; mt < 4; mt++){
        bf16x8 a = *(const bf16x8*)(fgw + (size_t)(w*64 + mt*16 + col)*O + ks*32 + kq*8);
        ac[mt] = MFMA(a, u.v, ac[mt]);
      }
    }
    bool cls = (w < 2);
    const float* b1p = cls ? cb1 : rb1;
    const float* w2p = cls ? cw2 : rw2;
    int jbase = (cls ? w : (w - 2)) * 64;
    float pp = 0.0f;
    for(int mt=0;mt<4;mt++) for(int r=0;r<4;r++){
      int j = jbase + mt*16 + kq*4 + r;
      pp += fmaxf(ac[mt][r] + b1p[j], 0.0f) * w2p[j];
    }
    pp += __shfl_xor(pp, 16); pp += __shfl_xor(pp, 32);
    if(kq == 0 && col < 2) pgsum[w][col] = pp;
  }
  __syncthreads();   // b7: pgsum visible

  // ======== stage I: final outputs ========
  {
    for(int qi = 0; qi < 2; qi++){
      float sC = 1.0f / (1.0f + expf(-(pgsum[0][qi] + pgsum[1][qi] + cb2[0])));
      float sR = 1.0f / (1.0f + expf(-(pgsum[2][qi] + pgsum[3][qi] + rb2[0])));
      int q = qg0 + qi;
      float nv = nfL[qi][t];
      outNF[(size_t)q*O + t] = nv;
      outC [(size_t)q*O + t] = nv * sC;
      outR [(size_t)q*O + t] = nv * sR;
    }
  }
}

extern "C" void kernel_launch(void* const* d_in, const int* in_sizes, int n_in,
                              void* d_out, int out_size, void* d_ws, size_t ws_size,
                              hipStream_t stream)
{
  const float* xyz  = (const float*)d_in[0];
  const float* nxyz = (const float*)d_in[1];
  const float* feat = (const float*)d_in[2];
  const float* posw = (const float*)d_in[3];
  const float* keyw = (const float*)d_in[4];
  const float* v1w  = (const float*)d_in[5];
  const float* bn1g = (const float*)d_in[6];
  const float* bn1b = (const float*)d_in[7];
  const float* v2w  = (const float*)d_in[8];
  const float* bn2g = (const float*)d_in[9];
  const float* bn2b = (const float*)d_in[10];
  const float* attw = (const float*)d_in[11];
  const float* kcw  = (const float*)d_in[12];
  const float* qcw  = (const float*)d_in[13];
  const float* qkcw = (const float*)d_in[14];
  const float* vcw  = (const float*)d_in[15];
  const float* cw1  = (const float*)d_in[16];
  const float* cb1  = (const float*)d_in[17];
  const float* cw2  = (const float*)d_in[18];
  const float* cb2  = (const float*)d_in[19];
  const float* rw1  = (const float*)d_in[20];
  const float* rb1  = (const float*)d_in[21];
  const float* rw2  = (const float*)d_in[22];
  const float* rb2  = (const float*)d_in[23];

  char* p = (char*)d_ws;
  auto alloc = [&](size_t bytes){ char* r = p; p += (bytes + 255) & ~size_t(255); return r; };
  short* fT    = (short*)alloc((size_t)NTOT*C*2);
  short* keyP  = (short*)alloc((size_t)O*C*2);
  short* v1P   = (short*)alloc((size_t)O*C*2);
  float* kgx   = (float*)alloc((size_t)O*4*4);
  float* v1gx  = (float*)alloc((size_t)O*4*4);
  float* pgx   = (float*)alloc((size_t)O*4*4);
  short* v2b   = (short*)alloc((size_t)O*O*2);
  short* gw    = (short*)alloc((size_t)4*O*O*2);
  short* fgw   = (short*)alloc((size_t)O*O*2);
  int*   idxw  = (int*)  alloc((size_t)M*NS*4);
  float* gxw   = (float*)alloc((size_t)M*NS*3*4);

  float* outNF = (float*)d_out;
  float* outC  = outNF + (size_t)M*O;
  float* outR  = outC  + (size_t)M*O;

  k_transpose<<<256, 256, 0, stream>>>(feat, fT);
  k_pack     <<<256, 256, 0, stream>>>(keyw, v1w, v2w, posw, vcw, qcw, kcw, qkcw, cw1, rw1,
                                       keyP, v1P, kgx, v1gx, pgx, v2b, gw, fgw);
  k_ballq    <<<M,   64,  0, stream>>>(xyz, nxyz, idxw, gxw);
  k_fused    <<<M/2, 256, 0, stream>>>(fT, keyP, v1P, kgx, v1gx, pgx, v2b, gw, fgw, attw,
                                       bn1g, bn1b, bn2g, bn2b,
                                       cb1, cw2, cb2, rb1, rw2, rb2,
                                       idxw, gxw, outNF, outC, outR);
}